// Round 14
// baseline (3113.594 us; speedup 1.0000x reference)
//
#include <hip/hip_runtime.h>
#include <cstddef>

#define NB 32
#define NT 512
#define ND 1024
#define NH 1024
#define NG 4096   // 4*NH
#define GRID 256  // 8 groups (blockIdx&7, 4 batch rows) x 32 slots (32 units)

typedef unsigned short ushortT;
typedef unsigned long long u64;
typedef __attribute__((ext_vector_type(8))) short short8;   // 8 bf16 = 4 VGPR
typedef __attribute__((ext_vector_type(4))) float f32x4;
typedef __attribute__((ext_vector_type(4))) unsigned uint4v;

#define GLL16(g, l) __builtin_amdgcn_global_load_lds(                      \
    (const __attribute__((address_space(1))) void*)(g),                    \
    (__attribute__((address_space(3))) void*)(l), 16, 0, 0)

__device__ __forceinline__ ushortT f2bf(float f) {
    union { float f; unsigned u; } v; v.f = f;
    unsigned r = v.u + 0x7FFFu + ((v.u >> 16) & 1u);   // RNE
    return (ushortT)(r >> 16);
}
__device__ __forceinline__ float bf2f(ushortT u) {
    union { unsigned u; float f; } v; v.u = (unsigned)u << 16; return v.f;
}

__device__ __forceinline__ float pick4(float a0, float a1, float a2, float a3, int s) {
    float lo = (s & 1) ? a1 : a0;
    float hi = (s & 1) ? a3 : a2;
    return (s & 2) ? hi : lo;
}

__device__ __forceinline__ float fsigmoid(float x) {
    return __builtin_amdgcn_rcpf(1.f + __expf(-x));
}
__device__ __forceinline__ float ftanh(float x) {
    float xc = fminf(fmaxf(x, -15.f), 15.f);
    float e  = __expf(-2.f * xc);
    return (1.f - e) * __builtin_amdgcn_rcpf(1.f + e);
}

// ---------------------------------------------------------------------------
__global__ __launch_bounds__(256) void cast_bf16(const float* __restrict__ src,
                                                 ushortT* __restrict__ dst, int n4)
{
    int i = blockIdx.x * 256 + threadIdx.x;
    if (i < n4) {
        float4 v = ((const float4*)src)[i];
        ushort4 o;
        o.x = f2bf(v.x); o.y = f2bf(v.y); o.z = f2bf(v.z); o.w = f2bf(v.w);
        ((ushort4*)dst)[i] = o;
    }
}

// ---------------------------------------------------------------------------
// h0 -> tagged pair buffer parity 0, tag 0. dst[row*512 + p] = pair(2p,2p+1)
// ---------------------------------------------------------------------------
__global__ __launch_bounds__(256) void cast_h0_tagged(
    const float* __restrict__ h0, u64* __restrict__ dst)
{
    int i = blockIdx.x * 256 + threadIdx.x;   // 0..16383
    int row = i >> 9, p = i & 511;
    unsigned pair = (unsigned)f2bf(h0[(size_t)row * NH + 2 * p])
                  | ((unsigned)f2bf(h0[(size_t)row * NH + 2 * p + 1]) << 16);
    dst[i] = (u64)pair;   // tag = 0
}

// ---------------------------------------------------------------------------
// transpose + cast: src f32 [1024][4096] -> dst bf16 [4096][1024]
// permute=1 remaps dst row n=(g*1024+j) -> (j>>2)*16 + g*4 + (j&3)
// ---------------------------------------------------------------------------
__global__ __launch_bounds__(256) void transpose_cast(
    const float* __restrict__ src, ushortT* __restrict__ dst, int permute)
{
    __shared__ ushortT tile[64][66];
    const int c0 = blockIdx.x * 64, r0 = blockIdx.y * 64;
    const int cc = threadIdx.x & 63, rq = threadIdx.x >> 6;
    #pragma unroll
    for (int ps = 0; ps < 16; ++ps) {
        int r = ps * 4 + rq;
        tile[cc][r] = f2bf(src[(size_t)(r0 + r) * NG + c0 + cc]);
    }
    __syncthreads();
    #pragma unroll
    for (int ps = 0; ps < 16; ++ps) {
        int cl = ps * 4 + rq;
        int n  = c0 + cl;
        int drow = permute ? ((((n & 1023) >> 2) << 4) | ((n >> 10) << 2) | (n & 3))
                           : n;
        dst[(size_t)drow * 1024 + r0 + cc] = tile[cl][cc];
    }
}

// ---------------------------------------------------------------------------
// xW GEMM, bf16 MFMA, global_load_lds staging (proven r7-r13).
// Epilogue: bf16 + permuted cols:  xwpb[(trel*NB+b)][perm(n)]
// ---------------------------------------------------------------------------
__global__ __launch_bounds__(256) void gemm_xw_mfma(
    const ushortT* __restrict__ xb,   // [NB*NT][ND] bf16
    const ushortT* __restrict__ wxT,  // [NG][ND]    bf16
    const float* __restrict__ bias,
    ushortT* __restrict__ XWPb,       // [Tc*NB][NG] bf16, permuted cols
    int t0, int Tc, int tcsh)
{
    __shared__ ushortT As[128 * 32];
    __shared__ ushortT Bs[128 * 32];

    const int tid  = threadIdx.x;
    const int lane = tid & 63;
    const int wv   = tid >> 6;
    const int wr   = wv >> 1, wc = wv & 1;
    const int n0   = blockIdx.x * 128;
    const int m0   = blockIdx.y * 128;

    const int c1 = tid, c2 = tid + 256;
    const int rm1 = m0 + (c1 >> 2), rm2 = m0 + (c2 >> 2);
    const int xr1 = ((rm1 >> tcsh) * NT) + t0 + (rm1 & (Tc - 1));
    const int xr2 = ((rm2 >> tcsh) * NT) + t0 + (rm2 & (Tc - 1));
    const ushortT* ap1 = xb + (size_t)xr1 * ND + (c1 & 3) * 8;
    const ushortT* ap2 = xb + (size_t)xr2 * ND + (c2 & 3) * 8;
    const ushortT* bp1 = wxT + (size_t)(n0 + (c1 >> 2)) * ND + (c1 & 3) * 8;
    const ushortT* bp2 = wxT + (size_t)(n0 + (c2 >> 2)) * ND + (c2 & 3) * 8;

    f32x4 acc[4][4];
    #pragma unroll
    for (int m = 0; m < 4; ++m)
        #pragma unroll
        for (int n = 0; n < 4; ++n) acc[m][n] = (f32x4){0.f, 0.f, 0.f, 0.f};

    const int arow_base = (wr * 64 + (lane & 15)) * 32 + (lane >> 4) * 8;
    const int brow_base = (wc * 64 + (lane & 15)) * 32 + (lane >> 4) * 8;

    for (int k0 = 0; k0 < ND; k0 += 32) {
        __syncthreads();
        GLL16(ap1 + k0, &As[c1 * 8]);
        GLL16(ap2 + k0, &As[c2 * 8]);
        GLL16(bp1 + k0, &Bs[c1 * 8]);
        GLL16(bp2 + k0, &Bs[c2 * 8]);
        __syncthreads();
        short8 af[4], bf[4];
        #pragma unroll
        for (int m = 0; m < 4; ++m)
            af[m] = *(const short8*)&As[arow_base + m * 16 * 32];
        #pragma unroll
        for (int n = 0; n < 4; ++n)
            bf[n] = *(const short8*)&Bs[brow_base + n * 16 * 32];
        #pragma unroll
        for (int m = 0; m < 4; ++m)
            #pragma unroll
            for (int n = 0; n < 4; ++n)
                acc[m][n] = __builtin_amdgcn_mfma_f32_16x16x32_bf16(
                    af[m], bf[n], acc[m][n], 0, 0, 0);
    }

    #pragma unroll
    for (int n = 0; n < 4; ++n) {
        int col = n0 + wc * 64 + n * 16 + (lane & 15);
        int pc  = (((col & 1023) >> 2) << 4) | ((col >> 10) << 2) | (col & 3);
        float bs = bias[col];
        #pragma unroll
        for (int m = 0; m < 4; ++m) {
            #pragma unroll
            for (int r = 0; r < 4; ++r) {
                int rm = m0 + wr * 64 + m * 16 + (lane >> 4) * 4 + r;
                int b  = rm >> tcsh, tr = rm & (Tc - 1);
                XWPb[((size_t)tr * NB + b) * NG + pc] = f2bf(acc[m][n][r] + bs);
            }
        }
    }
}

// ---------------------------------------------------------------------------
// Persistent LSTM recurrence, TAGGED-DATA exchange (no flags, no vmcnt
// fences, ONE barrier per step).
// grp = blockIdx&7 owns batch rows [4g,4g+4); sl = blockIdx>>3 owns hidden
// units [32sl,32sl+32). 8 waves split K 8-way; Wh register-resident.
// h word = 8B: lo32 = 2xbf16 pair, hi32 = tag (t+1 when storing h_t).
// Consumer at step t polls its OWN A-frag words in buf[t&1] until all
// tags == t (h0 pre-tagged 0). Tag and data arrive atomically in one word,
// so detection == availability: ~1 visibility latency per step.
// Safety (no flags needed): h_t value data-depends on all h_{t-1} reads,
// so "tag t+1 visible" => "that block's buf[t&1] reads done". A block's 8
// waves' polls cover ALL 32 producer blocks and the single barrier orders
// all polls before any store => overwrite of buf[par^1] is safe; skew > 1
// step within a group is impossible.
// ---------------------------------------------------------------------------
__global__ __launch_bounds__(512) void lstm_persist(
    const ushortT* __restrict__ XWPb,  // [Tc*NB][NG] bf16, permuted cols
    const ushortT* __restrict__ whpT,  // [4096][1024] permuted bf16
    u64* __restrict__ hbuf64,          // [2][32][512] tagged pairs
    const float* __restrict__ cinit,
    float* __restrict__ cT,
    float* __restrict__ out,           // [NB][NT][NH] f32
    float* __restrict__ hT,
    int t0, int Tc)
{
    __shared__ float red[2][64][16][4];   // 32 KB: [par][w*8+ct][col16][row]

    const int tid  = threadIdx.x;
    const int lane = tid & 63;
    const int w    = tid >> 6;            // K-split wave
    const int grp  = blockIdx.x & 7;
    const int sl   = blockIdx.x >> 3;

    const int lo = lane & 15;
    const int hi = lane >> 4;

    // Wh register residency: block cols [128sl,+128), wave k-units [128w,+128)
    short8 Bf[8][4];
    #pragma unroll
    for (int ct = 0; ct < 8; ++ct)
        #pragma unroll
        for (int ks = 0; ks < 4; ++ks)
            Bf[ct][ks] = *(const short8*)(whpT
                + (size_t)(sl * 128 + ct * 16 + lo) * NH + w * 128 + ks * 32 + hi * 8);

    // activation roles: thread -> (row, col) of the 4x128 block outputs
    const int arow = tid >> 7;            // 0..3
    const int acol = tid & 127;           // permuted col within block
    const int gq   = (acol >> 2) & 3;
    const int u4   = (acol >> 4) * 4 + (acol & 3);   // unit 0..31
    const int brow = grp * 4 + arow;
    const int j    = sl * 32 + u4;

    float creg = cinit[(size_t)brow * NH + j];

    // poll/A-frag source: row prow, pairs w*64 + ks*16 + hi*4 + q
    const int prow = grp * 4 + (lane & 3);
    const size_t pbase = (size_t)prow * 512 + w * 64 + hi * 4;
    // producer word: [par^1][brow][sl*16 + u4/2]
    const size_t wbase = (size_t)brow * 512 + sl * 16 + (u4 >> 1);

    ushortT xvr = XWPb[(size_t)brow * NG + sl * 128 + acol];

    const int tend = t0 + Tc;
    for (int t = t0; t < tend; ++t) {
        const int trel = t - t0;
        const int par  = t & 1;

        // ---- poll own A-frag tagged words until all tags == t ----
        const u64* rp = hbuf64 + (size_t)par * 16384 + pbase;
        u64 v0, v1, v2, v3, v4, v5, v6, v7, v8, v9, va, vb, vc, vd, ve, vf;
        const unsigned tgt = (unsigned)t;
        for (int it = 0; it < (1 << 17); ++it) {
            v0 = __hip_atomic_load(rp + 0,  __ATOMIC_RELAXED, __HIP_MEMORY_SCOPE_AGENT);
            v1 = __hip_atomic_load(rp + 1,  __ATOMIC_RELAXED, __HIP_MEMORY_SCOPE_AGENT);
            v2 = __hip_atomic_load(rp + 2,  __ATOMIC_RELAXED, __HIP_MEMORY_SCOPE_AGENT);
            v3 = __hip_atomic_load(rp + 3,  __ATOMIC_RELAXED, __HIP_MEMORY_SCOPE_AGENT);
            v4 = __hip_atomic_load(rp + 16, __ATOMIC_RELAXED, __HIP_MEMORY_SCOPE_AGENT);
            v5 = __hip_atomic_load(rp + 17, __ATOMIC_RELAXED, __HIP_MEMORY_SCOPE_AGENT);
            v6 = __hip_atomic_load(rp + 18, __ATOMIC_RELAXED, __HIP_MEMORY_SCOPE_AGENT);
            v7 = __hip_atomic_load(rp + 19, __ATOMIC_RELAXED, __HIP_MEMORY_SCOPE_AGENT);
            v8 = __hip_atomic_load(rp + 32, __ATOMIC_RELAXED, __HIP_MEMORY_SCOPE_AGENT);
            v9 = __hip_atomic_load(rp + 33, __ATOMIC_RELAXED, __HIP_MEMORY_SCOPE_AGENT);
            va = __hip_atomic_load(rp + 34, __ATOMIC_RELAXED, __HIP_MEMORY_SCOPE_AGENT);
            vb = __hip_atomic_load(rp + 35, __ATOMIC_RELAXED, __HIP_MEMORY_SCOPE_AGENT);
            vc = __hip_atomic_load(rp + 48, __ATOMIC_RELAXED, __HIP_MEMORY_SCOPE_AGENT);
            vd = __hip_atomic_load(rp + 49, __ATOMIC_RELAXED, __HIP_MEMORY_SCOPE_AGENT);
            ve = __hip_atomic_load(rp + 50, __ATOMIC_RELAXED, __HIP_MEMORY_SCOPE_AGENT);
            vf = __hip_atomic_load(rp + 51, __ATOMIC_RELAXED, __HIP_MEMORY_SCOPE_AGENT);
            bool ok = ((unsigned)(v0 >> 32) == tgt) & ((unsigned)(v1 >> 32) == tgt)
                    & ((unsigned)(v2 >> 32) == tgt) & ((unsigned)(v3 >> 32) == tgt)
                    & ((unsigned)(v4 >> 32) == tgt) & ((unsigned)(v5 >> 32) == tgt)
                    & ((unsigned)(v6 >> 32) == tgt) & ((unsigned)(v7 >> 32) == tgt)
                    & ((unsigned)(v8 >> 32) == tgt) & ((unsigned)(v9 >> 32) == tgt)
                    & ((unsigned)(va >> 32) == tgt) & ((unsigned)(vb >> 32) == tgt)
                    & ((unsigned)(vc >> 32) == tgt) & ((unsigned)(vd >> 32) == tgt)
                    & ((unsigned)(ve >> 32) == tgt) & ((unsigned)(vf >> 32) == tgt);
            if (__all(ok)) break;
        }

        // ---- build A fragments from data dwords ----
        uint4v d0 = (uint4v){(unsigned)v0, (unsigned)v1, (unsigned)v2, (unsigned)v3};
        uint4v d1 = (uint4v){(unsigned)v4, (unsigned)v5, (unsigned)v6, (unsigned)v7};
        uint4v d2 = (uint4v){(unsigned)v8, (unsigned)v9, (unsigned)va, (unsigned)vb};
        uint4v d3 = (uint4v){(unsigned)vc, (unsigned)vd, (unsigned)ve, (unsigned)vf};
        short8 A0 = *(short8*)&d0;
        short8 A1 = *(short8*)&d1;
        short8 A2 = *(short8*)&d2;
        short8 A3 = *(short8*)&d3;

        // ---- 32 MFMAs: 8 independent chains of 4 ----
        #pragma unroll
        for (int ct = 0; ct < 8; ++ct) {
            f32x4 a = (f32x4){0.f, 0.f, 0.f, 0.f};
            a = __builtin_amdgcn_mfma_f32_16x16x32_bf16(A0, Bf[ct][0], a, 0, 0, 0);
            a = __builtin_amdgcn_mfma_f32_16x16x32_bf16(A1, Bf[ct][1], a, 0, 0, 0);
            a = __builtin_amdgcn_mfma_f32_16x16x32_bf16(A2, Bf[ct][2], a, 0, 0, 0);
            a = __builtin_amdgcn_mfma_f32_16x16x32_bf16(A3, Bf[ct][3], a, 0, 0, 0);
            if (hi == 0)
                *(f32x4*)&red[par][w * 8 + ct][lo][0] = a;
        }
        __syncthreads();   // the ONE barrier: red visible; all polls done

        // ---- reduce 8 K-splits + xW -> own-gate preact ----
        float g = bf2f(xvr);
        #pragma unroll
        for (int wv = 0; wv < 8; ++wv)
            g += red[par][wv * 8 + (acol >> 4)][acol & 15][arow];

        float g4  = __shfl_xor(g, 4);
        float g8  = __shfl_xor(g, 8);
        float g12 = __shfl_xor(g, 12);

        float gi = pick4(g, g4, g8, g12, gq);
        float gf = pick4(g, g4, g8, g12, gq ^ 1);
        float gg = pick4(g, g4, g8, g12, gq ^ 2);
        float go = pick4(g, g4, g8, g12, gq ^ 3);

        float iv = fsigmoid(gi);
        float fv = fsigmoid(gf);
        float gv = ftanh(gg);
        float ov = fsigmoid(go);
        float cn = fv * creg + iv * gv;
        float hn = ov * ftanh(cn);
        creg = cn;

        // ---- tagged h store (fire-and-forget; tag rides with data) ----
        float ph = __shfl_xor(hn, 1);   // partner unit j^1
        const bool wl = (gq == 0) && ((acol & 1) == 0);
        if (wl) {
            unsigned pair = (unsigned)f2bf(hn) | ((unsigned)f2bf(ph) << 16);
            u64 word = (u64)pair | ((u64)(unsigned)(t + 1) << 32);
            __hip_atomic_store(hbuf64 + (size_t)(par ^ 1) * 16384 + wbase, word,
                               __ATOMIC_RELAXED, __HIP_MEMORY_SCOPE_AGENT);
        }

        // ---- off-critical-path outputs ----
        if (wl)
            *(float2*)&out[((size_t)brow * NT + t) * NH + j] = make_float2(hn, ph);
        if (t != tend - 1) {
            xvr = XWPb[((size_t)(trel + 1) * NB + brow) * NG + sl * 128 + acol];
        } else {
            if (gq == 0) {
                if (t == NT - 1) hT[(size_t)brow * NH + j] = hn;
                cT[(size_t)brow * NH + j] = cn;
            }
        }
    }
}

// ---------------------------------------------------------------------------
extern "C" void kernel_launch(void* const* d_in, const int* in_sizes, int n_in,
                              void* d_out, int out_size, void* d_ws, size_t ws_size,
                              hipStream_t stream) {
    const float* x    = (const float*)d_in[0];
    const float* c0   = (const float*)d_in[1];
    const float* h0   = (const float*)d_in[2];
    const float* Wx   = (const float*)d_in[3];
    const float* Wh   = (const float*)d_in[4];
    const float* bias = (const float*)d_in[5];

    float* out = (float*)d_out;
    float* cT  = out + (size_t)NB * NT * NH;
    float* hT  = cT + (size_t)NB * NH;

    // ws: xb 33.5MB | wxT 8.4MB | whpT 8.4MB | hbuf64 256KB | xwpb
    ushortT* xb   = (ushortT*)d_ws;
    ushortT* wxT  = xb  + (size_t)NB * NT * ND;
    ushortT* whpT = wxT + (size_t)NG * ND;
    u64*     hbuf64 = (u64*)(whpT + (size_t)NG * NH);   // 2*32*512 words
    ushortT* xwpb = (ushortT*)(hbuf64 + 2 * 32 * 512);

    const size_t fixed = ((size_t)NB * NT * ND + (size_t)NG * ND + (size_t)NG * NH
                          + 0) * sizeof(ushortT) + 2 * 32 * 512 * 8 + 256;
    int Tc = 512;
    while (Tc > 4 && fixed + (size_t)NB * Tc * NG * sizeof(ushortT) > ws_size)
        Tc >>= 1;
    int tcsh = 31 - __builtin_clz(Tc);

    cast_bf16<<<(NB * NT * ND / 4 + 255) / 256, 256, 0, stream>>>(x, xb, NB * NT * ND / 4);
    // tagged h0 -> buf[0]; zero buf[1] tags (poison/stale guard, once per call)
    cast_h0_tagged<<<64, 256, 0, stream>>>(h0, hbuf64);
    hipMemsetAsync(hbuf64 + 16384, 0, 16384 * sizeof(u64), stream);
    transpose_cast<<<dim3(64, 16), 256, 0, stream>>>(Wx, wxT, 0);
    transpose_cast<<<dim3(64, 16), 256, 0, stream>>>(Wh, whpT, 1);

    for (int t0 = 0; t0 < NT; t0 += Tc) {
        dim3 g(NG / 128, (NB * Tc) / 128);
        gemm_xw_mfma<<<g, 256, 0, stream>>>(xb, wxT, bias, xwpb, t0, Tc, tcsh);
        lstm_persist<<<GRID, 512, 0, stream>>>(
            xwpb, whpT, hbuf64,
            (t0 == 0) ? c0 : (const float*)cT,
            cT, out, hT, t0, Tc);
    }
}

// Round 15
// 2312.475 us; speedup vs baseline: 1.3464x; 1.3464x over previous
//
#include <hip/hip_runtime.h>
#include <cstddef>

#define NB 32
#define NT 512
#define ND 1024
#define NH 1024
#define NG 4096   // 4*NH
#define GRID 256  // 2 groups (blockIdx&1, 16 batch rows) x 128 slots (8 units)

typedef unsigned short ushortT;
typedef unsigned long long u64;
typedef __attribute__((ext_vector_type(8))) short short8;   // 8 bf16 = 4 VGPR
typedef __attribute__((ext_vector_type(4))) float f32x4;
typedef __attribute__((ext_vector_type(4))) unsigned uint4v;

#define GLL16(g, l) __builtin_amdgcn_global_load_lds(                      \
    (const __attribute__((address_space(1))) void*)(g),                    \
    (__attribute__((address_space(3))) void*)(l), 16, 0, 0)

__device__ __forceinline__ ushortT f2bf(float f) {
    union { float f; unsigned u; } v; v.f = f;
    unsigned r = v.u + 0x7FFFu + ((v.u >> 16) & 1u);   // RNE
    return (ushortT)(r >> 16);
}
__device__ __forceinline__ float bf2f(ushortT u) {
    union { unsigned u; float f; } v; v.u = (unsigned)u << 16; return v.f;
}

__device__ __forceinline__ float pick4(float a0, float a1, float a2, float a3, int s) {
    float lo = (s & 1) ? a1 : a0;
    float hi = (s & 1) ? a3 : a2;
    return (s & 2) ? hi : lo;
}

__device__ __forceinline__ float fsigmoid(float x) {
    return __builtin_amdgcn_rcpf(1.f + __expf(-x));
}
__device__ __forceinline__ float ftanh(float x) {
    float xc = fminf(fmaxf(x, -15.f), 15.f);
    float e  = __expf(-2.f * xc);
    return (1.f - e) * __builtin_amdgcn_rcpf(1.f + e);
}

// ---------------------------------------------------------------------------
__global__ __launch_bounds__(256) void cast_bf16(const float* __restrict__ src,
                                                 ushortT* __restrict__ dst, int n4)
{
    int i = blockIdx.x * 256 + threadIdx.x;
    if (i < n4) {
        float4 v = ((const float4*)src)[i];
        ushort4 o;
        o.x = f2bf(v.x); o.y = f2bf(v.y); o.z = f2bf(v.z); o.w = f2bf(v.w);
        ((ushort4*)dst)[i] = o;
    }
}

// ---------------------------------------------------------------------------
// transpose + cast: src f32 [1024][4096] -> dst bf16 [4096][1024]
// permute=1 remaps dst row n=(g*1024+j) -> (j>>2)*16 + g*4 + (j&3)
// ---------------------------------------------------------------------------
__global__ __launch_bounds__(256) void transpose_cast(
    const float* __restrict__ src, ushortT* __restrict__ dst, int permute)
{
    __shared__ ushortT tile[64][66];
    const int c0 = blockIdx.x * 64, r0 = blockIdx.y * 64;
    const int cc = threadIdx.x & 63, rq = threadIdx.x >> 6;
    #pragma unroll
    for (int ps = 0; ps < 16; ++ps) {
        int r = ps * 4 + rq;
        tile[cc][r] = f2bf(src[(size_t)(r0 + r) * NG + c0 + cc]);
    }
    __syncthreads();
    #pragma unroll
    for (int ps = 0; ps < 16; ++ps) {
        int cl = ps * 4 + rq;
        int n  = c0 + cl;
        int drow = permute ? ((((n & 1023) >> 2) << 4) | ((n >> 10) << 2) | (n & 3))
                           : n;
        dst[(size_t)drow * 1024 + r0 + cc] = tile[cl][cc];
    }
}

// ---------------------------------------------------------------------------
// xW GEMM, bf16 MFMA, global_load_lds staging (proven r7-r14).
// Epilogue: bf16 + permuted cols:  xwpb[(trel*NB+b)][perm(n)]
// ---------------------------------------------------------------------------
__global__ __launch_bounds__(256) void gemm_xw_mfma(
    const ushortT* __restrict__ xb,   // [NB*NT][ND] bf16
    const ushortT* __restrict__ wxT,  // [NG][ND]    bf16
    const float* __restrict__ bias,
    ushortT* __restrict__ XWPb,       // [Tc*NB][NG] bf16, permuted cols
    int t0, int Tc, int tcsh)
{
    __shared__ ushortT As[128 * 32];
    __shared__ ushortT Bs[128 * 32];

    const int tid  = threadIdx.x;
    const int lane = tid & 63;
    const int wv   = tid >> 6;
    const int wr   = wv >> 1, wc = wv & 1;
    const int n0   = blockIdx.x * 128;
    const int m0   = blockIdx.y * 128;

    const int c1 = tid, c2 = tid + 256;
    const int rm1 = m0 + (c1 >> 2), rm2 = m0 + (c2 >> 2);
    const int xr1 = ((rm1 >> tcsh) * NT) + t0 + (rm1 & (Tc - 1));
    const int xr2 = ((rm2 >> tcsh) * NT) + t0 + (rm2 & (Tc - 1));
    const ushortT* ap1 = xb + (size_t)xr1 * ND + (c1 & 3) * 8;
    const ushortT* ap2 = xb + (size_t)xr2 * ND + (c2 & 3) * 8;
    const ushortT* bp1 = wxT + (size_t)(n0 + (c1 >> 2)) * ND + (c1 & 3) * 8;
    const ushortT* bp2 = wxT + (size_t)(n0 + (c2 >> 2)) * ND + (c2 & 3) * 8;

    f32x4 acc[4][4];
    #pragma unroll
    for (int m = 0; m < 4; ++m)
        #pragma unroll
        for (int n = 0; n < 4; ++n) acc[m][n] = (f32x4){0.f, 0.f, 0.f, 0.f};

    const int arow_base = (wr * 64 + (lane & 15)) * 32 + (lane >> 4) * 8;
    const int brow_base = (wc * 64 + (lane & 15)) * 32 + (lane >> 4) * 8;

    for (int k0 = 0; k0 < ND; k0 += 32) {
        __syncthreads();
        GLL16(ap1 + k0, &As[c1 * 8]);
        GLL16(ap2 + k0, &As[c2 * 8]);
        GLL16(bp1 + k0, &Bs[c1 * 8]);
        GLL16(bp2 + k0, &Bs[c2 * 8]);
        __syncthreads();
        short8 af[4], bf[4];
        #pragma unroll
        for (int m = 0; m < 4; ++m)
            af[m] = *(const short8*)&As[arow_base + m * 16 * 32];
        #pragma unroll
        for (int n = 0; n < 4; ++n)
            bf[n] = *(const short8*)&Bs[brow_base + n * 16 * 32];
        #pragma unroll
        for (int m = 0; m < 4; ++m)
            #pragma unroll
            for (int n = 0; n < 4; ++n)
                acc[m][n] = __builtin_amdgcn_mfma_f32_16x16x32_bf16(
                    af[m], bf[n], acc[m][n], 0, 0, 0);
    }

    #pragma unroll
    for (int n = 0; n < 4; ++n) {
        int col = n0 + wc * 64 + n * 16 + (lane & 15);
        int pc  = (((col & 1023) >> 2) << 4) | ((col >> 10) << 2) | (col & 3);
        float bs = bias[col];
        #pragma unroll
        for (int m = 0; m < 4; ++m) {
            #pragma unroll
            for (int r = 0; r < 4; ++r) {
                int rm = m0 + wr * 64 + m * 16 + (lane >> 4) * 4 + r;
                int b  = rm >> tcsh, tr = rm & (Tc - 1);
                XWPb[((size_t)tr * NB + b) * NG + pc] = f2bf(acc[m][n][r] + bs);
            }
        }
    }
}

// ---------------------------------------------------------------------------
// Persistent LSTM recurrence = r9 (best measured) + two shavings:
//   (1) direct global A-frag loads (no LDS h staging round trip)
//   (2) red double-buffered by parity -> ONE __syncthreads per step
// grp = blockIdx&1 owns batch rows [16g,16g+16); s = blockIdx>>1 owns units
// [8s,8s+8) = permuted gate cols [32s,32s+32). 8 waves split K 8-way
// (units [128w,128w+128)); Wh register-resident (Bf[2][4] = 32 VGPR).
// Sync (r9-proven): per-WAVE flags; producer: h stores -> wave vmcnt(0) ->
// lane0 stores flag=trel+1; consumer wave polls its 128 producer-wave flags
// (2/lane, one 8B load). h double-buffer safety: the 8 waves' polls jointly
// cover all 1024 group flags, and SYNC1 orders all polls before any h store.
// ---------------------------------------------------------------------------
__global__ __launch_bounds__(512) void lstm_persist(
    const ushortT* __restrict__ XWPb,  // [Tc*NB][NG] bf16, permuted cols
    const ushortT* __restrict__ whpT,  // [4096][1024] permuted bf16
    unsigned* __restrict__ hb0,        // [32][512] dwords (2xbf16), parity 0
    unsigned* __restrict__ hb1,        // parity 1 (h0 here)
    const float* __restrict__ cinit,
    float* __restrict__ cT,
    float* __restrict__ out,           // [NB][NT][NH] f32
    float* __restrict__ hT,
    unsigned* __restrict__ flags,      // [2][1024], zeroed per launch
    int t0, int Tc)
{
    __shared__ float red[2][16 * 272];   // 34 KB: [par][(w*2+ct)*272 + row*17 + col]

    const int tid  = threadIdx.x;
    const int lane = tid & 63;
    const int w    = tid >> 6;          // K-split wave: units [128w,128w+128)
    const int grp  = blockIdx.x & 1;
    const int s    = blockIdx.x >> 1;   // 0..127

    const int lo = lane & 15;
    const int hi = lane >> 4;

    // reduction/activation roles
    const int rrow  = tid >> 5;         // 0..15 batch row (within group)
    const int col32 = tid & 31;         // perm col within block
    const int rct   = col32 >> 4, rc16 = col32 & 15;
    const int gq    = (col32 >> 2) & 3;
    const int uu    = (col32 >> 4) * 4 + (col32 & 3);   // unit 0..7
    const int j     = s * 8 + uu;
    const int brow  = grp * 16 + rrow;

    // Wh register residency: Bf[ct][ks], 32 VGPR
    short8 Bf[2][4];
    #pragma unroll
    for (int ct = 0; ct < 2; ++ct)
        #pragma unroll
        for (int ks = 0; ks < 4; ++ks)
            Bf[ct][ks] = *(const short8*)(whpT
                + (size_t)(s * 32 + ct * 16 + lo) * NH + w * 128 + ks * 32 + hi * 8);

    float creg = cinit[(size_t)brow * NH + j];

    // direct A-frag source (u64 index): row lo, 16B chunk at unit w*128+ks*32+hi*8
    const size_t abase64 = (size_t)lo * 256 + w * 32 + hi * 2;

    unsigned* const gf = flags + grp * 1024;
    // wave w consumes units [128w,+128) -> producer-wave flags [128w,128w+128)
    const u64* fp = (const u64*)(gf + 128 * w + 2 * lane);
    unsigned* const fmine = gf + s * 8 + w;

    ushortT xvr = XWPb[(size_t)brow * NG + s * 32 + col32];

    const int tend = t0 + Tc;
    for (int t = t0; t < tend; ++t) {
        const int trel = t - t0;
        const int par  = t & 1;
        const unsigned* hR = ((t & 1) ? hb0 : hb1) + grp * 8192;  // h_{t-1}
        unsigned*       hW = ((t & 1) ? hb1 : hb0) + grp * 8192;  // h_t

        // ---- wave-autonomous wait for this wave's producers ----
        if (trel) {
            const unsigned tgt = (unsigned)trel;
            for (int it = 0; it < (1 << 17); ++it) {
                u64 v = __hip_atomic_load(fp, __ATOMIC_RELAXED,
                                          __HIP_MEMORY_SCOPE_AGENT);
                bool ok = ((unsigned)v >= tgt) && ((unsigned)(v >> 32) >= tgt);
                if (__all(ok)) break;
            }
        }

        // ---- A-fragments DIRECT from h buffer (agent 8B atomic loads) ----
        const u64* ap = (const u64*)hR + abase64;
        u64 q0, q1;
        uint4v d0, d1, d2, d3;
        q0 = __hip_atomic_load(ap + 0,  __ATOMIC_RELAXED, __HIP_MEMORY_SCOPE_AGENT);
        q1 = __hip_atomic_load(ap + 1,  __ATOMIC_RELAXED, __HIP_MEMORY_SCOPE_AGENT);
        d0 = (uint4v){(unsigned)q0, (unsigned)(q0 >> 32), (unsigned)q1, (unsigned)(q1 >> 32)};
        q0 = __hip_atomic_load(ap + 8,  __ATOMIC_RELAXED, __HIP_MEMORY_SCOPE_AGENT);
        q1 = __hip_atomic_load(ap + 9,  __ATOMIC_RELAXED, __HIP_MEMORY_SCOPE_AGENT);
        d1 = (uint4v){(unsigned)q0, (unsigned)(q0 >> 32), (unsigned)q1, (unsigned)(q1 >> 32)};
        q0 = __hip_atomic_load(ap + 16, __ATOMIC_RELAXED, __HIP_MEMORY_SCOPE_AGENT);
        q1 = __hip_atomic_load(ap + 17, __ATOMIC_RELAXED, __HIP_MEMORY_SCOPE_AGENT);
        d2 = (uint4v){(unsigned)q0, (unsigned)(q0 >> 32), (unsigned)q1, (unsigned)(q1 >> 32)};
        q0 = __hip_atomic_load(ap + 24, __ATOMIC_RELAXED, __HIP_MEMORY_SCOPE_AGENT);
        q1 = __hip_atomic_load(ap + 25, __ATOMIC_RELAXED, __HIP_MEMORY_SCOPE_AGENT);
        d3 = (uint4v){(unsigned)q0, (unsigned)(q0 >> 32), (unsigned)q1, (unsigned)(q1 >> 32)};

        short8 A0 = *(short8*)&d0;
        short8 A1 = *(short8*)&d1;
        short8 A2 = *(short8*)&d2;
        short8 A3 = *(short8*)&d3;

        // ---- 8 MFMAs: 2 independent chains (col-tiles share A) ----
        f32x4 acc0 = (f32x4){0.f, 0.f, 0.f, 0.f};
        f32x4 acc1 = (f32x4){0.f, 0.f, 0.f, 0.f};
        acc0 = __builtin_amdgcn_mfma_f32_16x16x32_bf16(A0, Bf[0][0], acc0, 0, 0, 0);
        acc1 = __builtin_amdgcn_mfma_f32_16x16x32_bf16(A0, Bf[1][0], acc1, 0, 0, 0);
        acc0 = __builtin_amdgcn_mfma_f32_16x16x32_bf16(A1, Bf[0][1], acc0, 0, 0, 0);
        acc1 = __builtin_amdgcn_mfma_f32_16x16x32_bf16(A1, Bf[1][1], acc1, 0, 0, 0);
        acc0 = __builtin_amdgcn_mfma_f32_16x16x32_bf16(A2, Bf[0][2], acc0, 0, 0, 0);
        acc1 = __builtin_amdgcn_mfma_f32_16x16x32_bf16(A2, Bf[1][2], acc1, 0, 0, 0);
        acc0 = __builtin_amdgcn_mfma_f32_16x16x32_bf16(A3, Bf[0][3], acc0, 0, 0, 0);
        acc1 = __builtin_amdgcn_mfma_f32_16x16x32_bf16(A3, Bf[1][3], acc1, 0, 0, 0);

        #pragma unroll
        for (int r = 0; r < 4; ++r) {
            red[par][(w * 2 + 0) * 272 + (hi * 4 + r) * 17 + lo] = acc0[r];
            red[par][(w * 2 + 1) * 272 + (hi * 4 + r) * 17 + lo] = acc1[r];
        }
        __syncthreads();   // SYNC1 (the only barrier): red[par] visible;
                           // all 8 waves' polls have completed

        // ---- reduce 8 K-splits + xW -> own-gate preact ----
        float g = bf2f(xvr);
        #pragma unroll
        for (int wv = 0; wv < 8; ++wv)
            g += red[par][(wv * 2 + rct) * 272 + rrow * 17 + rc16];

        float g4  = __shfl_xor(g, 4);
        float g8  = __shfl_xor(g, 8);
        float g12 = __shfl_xor(g, 12);

        float gi = pick4(g, g4, g8, g12, gq);
        float gf = pick4(g, g4, g8, g12, gq ^ 1);
        float gg = pick4(g, g4, g8, g12, gq ^ 2);
        float go = pick4(g, g4, g8, g12, gq ^ 3);

        float iv = fsigmoid(gi);
        float fv = fsigmoid(gf);
        float gv = ftanh(gg);
        float ov = fsigmoid(go);
        float cn = fv * creg + iv * gv;
        float hn = ov * ftanh(cn);
        creg = cn;

        float ph = __shfl_xor(hn, 1);   // partner unit j^1
        const bool wl = (gq == 0) && ((col32 & 1) == 0);
        if (wl) {
            unsigned pair = (unsigned)f2bf(hn) | ((unsigned)f2bf(ph) << 16);
            __hip_atomic_store(&hW[rrow * 512 + (j >> 1)], pair,
                               __ATOMIC_RELAXED, __HIP_MEMORY_SCOPE_AGENT);
        }

        if (t != tend - 1) {
            // wave-local drain of h stores, then publish per-wave flag
            asm volatile("s_waitcnt vmcnt(0)" ::: "memory");
            if (lane == 0)
                __hip_atomic_store(fmine, (unsigned)(trel + 1),
                                   __ATOMIC_RELAXED, __HIP_MEMORY_SCOPE_AGENT);
            // off-critical-path: out store + next-step xW prefetch
            if (wl)
                *(float2*)&out[((size_t)brow * NT + t) * NH + j] = make_float2(hn, ph);
            xvr = XWPb[((size_t)(trel + 1) * NB + brow) * NG + s * 32 + col32];
        } else {
            if (wl)
                *(float2*)&out[((size_t)brow * NT + t) * NH + j] = make_float2(hn, ph);
            if (gq == 0) {
                if (t == NT - 1) hT[(size_t)brow * NH + j] = hn;
                cT[(size_t)brow * NH + j] = cn;
            }
        }
    }
}

// ---------------------------------------------------------------------------
extern "C" void kernel_launch(void* const* d_in, const int* in_sizes, int n_in,
                              void* d_out, int out_size, void* d_ws, size_t ws_size,
                              hipStream_t stream) {
    const float* x    = (const float*)d_in[0];
    const float* c0   = (const float*)d_in[1];
    const float* h0   = (const float*)d_in[2];
    const float* Wx   = (const float*)d_in[3];
    const float* Wh   = (const float*)d_in[4];
    const float* bias = (const float*)d_in[5];

    float* out = (float*)d_out;
    float* cT  = out + (size_t)NB * NT * NH;
    float* hT  = cT + (size_t)NB * NH;

    // ws: xb 33.5MB | wxT 8.4MB | whpT 8.4MB | hb0 64KB | hb1 64KB | flags 8KB | xwpb
    ushortT* xb   = (ushortT*)d_ws;
    ushortT* wxT  = xb  + (size_t)NB * NT * ND;
    ushortT* whpT = wxT + (size_t)NG * ND;
    unsigned* hb0 = (unsigned*)(whpT + (size_t)NG * NH);
    unsigned* hb1 = hb0 + NB * NH / 2;
    unsigned* flags = hb1 + NB * NH / 2;
    ushortT* xwpb = (ushortT*)(flags + 2 * 1024);

    const size_t fixed = ((size_t)NB * NT * ND + (size_t)NG * ND + (size_t)NG * NH
                          + 2 * NB * NH) * sizeof(ushortT) + 2 * 1024 * 4 + 256;
    int Tc = 512;
    while (Tc > 4 && fixed + (size_t)NB * Tc * NG * sizeof(ushortT) > ws_size)
        Tc >>= 1;
    int tcsh = 31 - __builtin_clz(Tc);

    cast_bf16<<<(NB * NT * ND / 4 + 255) / 256, 256, 0, stream>>>(x, xb, NB * NT * ND / 4);
    // h0 -> hb1 (parity-1 buffer: hR at t=0)
    cast_bf16<<<(NB * NH / 4 + 255) / 256, 256, 0, stream>>>(h0, (ushortT*)hb1, NB * NH / 4);
    transpose_cast<<<dim3(64, 16), 256, 0, stream>>>(Wx, wxT, 0);
    transpose_cast<<<dim3(64, 16), 256, 0, stream>>>(Wh, whpT, 1);

    for (int t0 = 0; t0 < NT; t0 += Tc) {
        dim3 g(NG / 128, (NB * Tc) / 128);
        gemm_xw_mfma<<<g, 256, 0, stream>>>(xb, wxT, bias, xwpb, t0, Tc, tcsh);
        hipMemsetAsync(flags, 0, 2 * 1024 * sizeof(unsigned), stream);
        lstm_persist<<<GRID, 512, 0, stream>>>(
            xwpb, whpT, hb0, hb1,
            (t0 == 0) ? c0 : (const float*)cT,
            cT, out, hT, flags, t0, Tc);
    }
}